// Round 6
// baseline (473.861 us; speedup 1.0000x reference)
//
#include <hip/hip_runtime.h>
#include <hip/hip_fp16.h>
#include <math.h>

#define NN 50000
#define NE 600000
#define NT ((NN + 31) / 32)   // 1563 row-tiles of 32

typedef _Float16 half8_t __attribute__((ext_vector_type(8)));
typedef float f32x16 __attribute__((ext_vector_type(16)));

union F2H { float2 f; __half2 h[2]; };
union HV { float4 f4; __half2 h2[4]; };

// Packed fragment layout for MFMA (32x32x16_f16):
//   element (row r in tile t, feature k): ks=k>>4, g=(k&15)>>3, j=k&7
//   halves index = ((t*8 + ks)*64 + g*32 + r)*8 + j   (per 128-k buffer)

// ---------------- tanh + dual fp16 write (plain and *norm_o) ----------------
__global__ __launch_bounds__(256) void k_tanh(const float* __restrict__ x,
                                              const float* __restrict__ no,
                                              __half2* __restrict__ x0h,
                                              __half2* __restrict__ x0n) {
  int i = blockIdx.x * 256 + threadIdx.x;
  if (i >= NN * 32) return;
  float4 v = reinterpret_cast<const float4*>(x)[i];
  float t[4];
  float vv[4] = {v.x, v.y, v.z, v.w};
  #pragma unroll
  for (int j = 0; j < 4; ++j) {
    float xc = fminf(fmaxf(vv[j], -9.f), 9.f);
    float E = __expf(2.f * xc);
    t[j] = (E - 1.f) / (E + 1.f);
  }
  float s = no[i >> 5];  // 32 float4 per node row
  F2H a, b;
  a.h[0] = __floats2half2_rn(t[0], t[1]);
  a.h[1] = __floats2half2_rn(t[2], t[3]);
  b.h[0] = __floats2half2_rn(t[0] * s, t[1] * s);
  b.h[1] = __floats2half2_rn(t[2] * s, t[3] * s);
  reinterpret_cast<float2*>(x0h)[i] = a.f;
  reinterpret_cast<float2*>(x0n)[i] = b.f;
}

// ------------- W transpose -> fragment-packed fp16 (runs once, tiny) --------
__global__ __launch_bounds__(256) void k_wt(const float* __restrict__ W1,
                                            const float* __restrict__ W2,
                                            _Float16* __restrict__ w1p,
                                            _Float16* __restrict__ w2p) {
  int i = blockIdx.x * 256 + threadIdx.x;
  if (i < 128 * 128) {
    int k = i >> 7, n = i & 127;
    int nb = n >> 5, r = n & 31, ks = k >> 4, g = (k & 15) >> 3, j = k & 7;
    w1p[(((ks << 2) + nb) * 64 + (g << 5) + r) * 8 + j] = (_Float16)W1[i];
  } else {
    int q = i - 128 * 128;
    if (q < 256 * 128) {
      int k = q >> 7, n = q & 127;
      int nb = n >> 5, r = n & 31, ks = k >> 4, g = (k & 15) >> 3, j = k & 7;
      w2p[(((ks << 2) + nb) * 64 + (g << 5) + r) * 8 + j] = (_Float16)W2[q];
    }
  }
}

// ------- CSR build: seq-fill (1.2M atomics total) + scan + free scatter -----
__global__ __launch_bounds__(256) void k_fill2(const int* __restrict__ src,
                                               const int* __restrict__ dst,
                                               int* __restrict__ co,
                                               int* __restrict__ fillc,
                                               int* __restrict__ tseq) {
  int e = blockIdx.x * 256 + threadIdx.x;
  if (e < NE) {
    atomicAdd(&co[src[e]], 1);                 // out-degree (fire-and-forget)
    tseq[e] = atomicAdd(&fillc[dst[e]], 1);    // in-degree + sequence number
  }
}

__global__ __launch_bounds__(256) void k_scatter(const int* __restrict__ src,
                                                 const int* __restrict__ dst,
                                                 const int* __restrict__ tseq,
                                                 const int* __restrict__ rp,
                                                 int* __restrict__ colsrc) {
  int e = blockIdx.x * 256 + threadIdx.x;
  if (e < NE) colsrc[rp[dst[e]] + tseq[e]] = src[e];
}

__global__ __launch_bounds__(256) void k_norm(const int* __restrict__ co,
                                              const int* __restrict__ ci,
                                              float* __restrict__ no,
                                              float* __restrict__ ni) {
  int i = blockIdx.x * 256 + threadIdx.x;
  if (i < NN) {
    no[i] = rsqrtf((float)max(co[i], 1));
    ni[i] = rsqrtf((float)max(ci[i], 1));
  }
}

// ---------------- exclusive scan of in-degrees ----------------
__global__ __launch_bounds__(1024) void k_scanA(const int* __restrict__ deg,
                                                int* __restrict__ incl,
                                                int* __restrict__ bsum) {
  int tid = threadIdx.x;
  int gid = blockIdx.x * 1024 + tid;
  int v = (gid < NN) ? deg[gid] : 0;
  int lane = tid & 63;
  #pragma unroll
  for (int o = 1; o < 64; o <<= 1) {
    int n = __shfl_up(v, o);
    if (lane >= o) v += n;
  }
  __shared__ int ws[16];
  int wid = tid >> 6;
  if (lane == 63) ws[wid] = v;
  __syncthreads();
  if (tid < 16) {
    int s = ws[tid];
    #pragma unroll
    for (int o = 1; o < 16; o <<= 1) {
      int n = __shfl_up(s, o);
      if (tid >= o) s += n;
    }
    ws[tid] = s;
  }
  __syncthreads();
  if (wid > 0) v += ws[wid - 1];
  if (gid < NN) incl[gid] = v;
  if (tid == 1023) bsum[blockIdx.x] = v;
}

__global__ __launch_bounds__(64) void k_scanB(const int* __restrict__ bsum,
                                              int* __restrict__ boff, int nb) {
  int t = threadIdx.x;
  int v = (t < nb) ? bsum[t] : 0;
  int orig = v;
  #pragma unroll
  for (int o = 1; o < 64; o <<= 1) {
    int n = __shfl_up(v, o);
    if (t >= o) v += n;
  }
  if (t < nb) boff[t] = v - orig;  // exclusive
}

__global__ __launch_bounds__(256) void k_scanC(const int* __restrict__ incl,
                                               const int* __restrict__ deg,
                                               const int* __restrict__ boff,
                                               int* __restrict__ rp) {
  int i = blockIdx.x * 256 + threadIdx.x;
  if (i < NN) rp[i] = incl[i] - deg[i] + boff[i >> 10];
  if (i == 0) rp[NN] = NE;
}

// ---- half-split gather core: 8 lanes x 16B per edge, 8 edges per wave-load.
// Accumulates the wave's node's features [half*64 + (lane&7)*8 .. +8) in a[4].
__device__ __forceinline__ void gather_half(const float4* __restrict__ hf4,
                                            int half, int beg, int end,
                                            const int* __restrict__ cs,
                                            int lane, float2* a) {
  int grp = lane >> 3, sub = lane & 7;
  const float4* hb = hf4 + half * 8 + sub;
  int cnt = end - beg;
  for (int base = 0; base < cnt; base += 64) {
    int e = beg + base + lane;
    int cv = (e < end) ? cs[e] : 0;
    int m = cnt - base; if (m > 64) m = 64;
    for (int j = 0; j < m; j += 8) {
      int idx = j + grp;
      int s = __shfl(cv, idx < m ? idx : m - 1);
      float sel = idx < m ? 1.0f : 0.0f;
      HV u;
      u.f4 = hb[(size_t)s * 16];
      #pragma unroll
      for (int i = 0; i < 4; ++i) {
        float2 f = __half22float2(u.h2[i]);
        a[i].x = fmaf(sel, f.x, a[i].x);
        a[i].y = fmaf(sel, f.y, a[i].y);
      }
    }
  }
  #pragma unroll
  for (int i = 0; i < 4; ++i) {
    #pragma unroll
    for (int off = 8; off < 64; off <<= 1) {
      a[i].x += __shfl_xor(a[i].x, off);
      a[i].y += __shfl_xor(a[i].y, off);
    }
  }
}

// ---- APPNP half-iteration: out = [no*] (0.8*ni*sum(h_scaled[s]) + 0.2*x0) --
template <bool SCALE_OUT>
__global__ __launch_bounds__(256) void k_appnp_h(const float4* __restrict__ h,
                                                 const float4* __restrict__ x0,
                                                 const float* __restrict__ no,
                                                 const float* __restrict__ ni,
                                                 const int* __restrict__ rp,
                                                 const int* __restrict__ cs,
                                                 float4* __restrict__ outp,
                                                 int half) {
  int w = (blockIdx.x * 256 + threadIdx.x) >> 6;
  int lane = threadIdx.x & 63;
  if (w >= NN) return;
  int beg = rp[w], end = rp[w + 1];
  float2 a[4] = {{0.f, 0.f}, {0.f, 0.f}, {0.f, 0.f}, {0.f, 0.f}};
  gather_half(h, half, beg, end, cs, lane, a);
  if (lane < 8) {
    HV xu, ou;
    xu.f4 = x0[(size_t)w * 16 + half * 8 + lane];
    float wi = 0.8f * ni[w];
    float sc = SCALE_OUT ? no[w] : 1.0f;
    #pragma unroll
    for (int i = 0; i < 4; ++i) {
      float2 xf = __half22float2(xu.h2[i]);
      ou.h2[i] = __floats2half2_rn(sc * (wi * a[i].x + 0.2f * xf.x),
                                   sc * (wi * a[i].y + 0.2f * xf.y));
    }
    outp[(size_t)w * 16 + half * 8 + lane] = ou.f4;
  }
}

// ---- gather + GIN affine half-pass, packed store: z = (1+eps)*h[w]+sum(h[s])
__global__ __launch_bounds__(256) void k_gz_h(const float4* __restrict__ h,
                                              const float* __restrict__ epsp,
                                              const int* __restrict__ rp,
                                              const int* __restrict__ cs,
                                              _Float16* __restrict__ zout,
                                              int half) {
  int w = (blockIdx.x * 256 + threadIdx.x) >> 6;
  int lane = threadIdx.x & 63;
  if (w >= NN) return;
  int beg = rp[w], end = rp[w + 1];
  float2 a[4] = {{0.f, 0.f}, {0.f, 0.f}, {0.f, 0.f}, {0.f, 0.f}};
  gather_half(h, half, beg, end, cs, lane, a);
  if (lane < 8) {
    int sub = lane;
    HV xu, ou;
    xu.f4 = h[(size_t)w * 16 + half * 8 + sub];
    float e1 = 1.0f + epsp[0];
    #pragma unroll
    for (int i = 0; i < 4; ++i) {
      float2 xf = __half22float2(xu.h2[i]);
      ou.h2[i] = __floats2half2_rn(e1 * xf.x + a[i].x, e1 * xf.y + a[i].y);
    }
    int t = w >> 5, r = w & 31;
    size_t zaddr = (((size_t)t * 8 + half * 4 + (sub >> 1)) * 64 +
                    (sub & 1) * 32 + r) * 8;
    *reinterpret_cast<float4*>(zout + zaddr) = ou.f4;
  }
}

// ---- MFMA GEMM on packed operands: C = Z @ W + b -------------------------
template <int KTOT, bool MISH>
__global__ __launch_bounds__(64) void k_mgemm(const _Float16* __restrict__ z0,
                                              const _Float16* __restrict__ z1,
                                              const _Float16* __restrict__ wp,
                                              const float* __restrict__ bias,
                                              float* __restrict__ outf,
                                              __half2* __restrict__ outh) {
  int lane = threadIdx.x;
  int t = blockIdx.x;
  int row0 = t * 32;
  if (row0 >= NN) return;
  int r31 = lane & 31, g = lane >> 5;
  f32x16 acc[4];
  #pragma unroll
  for (int i = 0; i < 4; ++i) acc[i] = (f32x16)(0.0f);
  #pragma unroll 4
  for (int ks = 0; ks < KTOT / 16; ++ks) {
    const _Float16* zp = (KTOT == 256 && ks >= 8) ? z1 : z0;
    int kls = (KTOT == 256) ? (ks & 7) : ks;
    half8_t a = *reinterpret_cast<const half8_t*>(
        zp + (((size_t)t * 8 + kls) * 64 + lane) * 8);
    #pragma unroll
    for (int nb = 0; nb < 4; ++nb) {
      half8_t b = *reinterpret_cast<const half8_t*>(
          wp + (((size_t)ks * 4 + nb) * 64 + lane) * 8);
      acc[nb] = __builtin_amdgcn_mfma_f32_32x32x16_f16(a, b, acc[nb], 0, 0, 0);
    }
  }
  #pragma unroll
  for (int nb = 0; nb < 4; ++nb) {
    float bv = bias[nb * 32 + r31];
    #pragma unroll
    for (int r = 0; r < 16; ++r) {
      int rl = (r & 3) + 8 * (r >> 2) + 4 * g;
      int grow = row0 + rl;
      if (grow < NN) {
        float v = acc[nb][r] + bv;
        if (MISH) {
          // mish(v) = v*q/(q+2), q = E(E+2), E = e^v
          float E = __expf(v);
          float q = E * (E + 2.f);
          float mv = v * q / (q + 2.f);
          v = (v > 15.f) ? v : mv;
          outf[(size_t)grow * 128 + nb * 32 + r31] = v;
        } else {
          float u = __shfl_xor(v, 1);
          if (!(lane & 1)) {
            outh[((size_t)grow * 128 + nb * 32 + r31) >> 1] = __floats2half2_rn(v, u);
          }
        }
      }
    }
  }
}

extern "C" void kernel_launch(void* const* d_in, const int* in_sizes, int n_in,
                              void* d_out, int out_size, void* d_ws, size_t ws_size,
                              hipStream_t stream) {
  const float* x = (const float*)d_in[0];
  const int* src = (const int*)d_in[1];
  const int* dst = (const int*)d_in[2];
  const float* W1 = (const float*)d_in[3];
  const float* b1 = (const float*)d_in[4];
  const float* W2 = (const float*)d_in[5];
  const float* b2 = (const float*)d_in[6];
  const float* eps1 = (const float*)d_in[7];
  const float* eps2 = (const float*)d_in[8];
  float* out = (float*)d_out;

  char* ws = (char*)d_ws;
  size_t off = 0;
  auto alloc = [&](size_t bytes) -> void* {
    void* p = ws + off;
    off += (bytes + 255) & ~(size_t)255;
    return p;
  };
  const size_t NDP = (size_t)NT * 4096;  // halves per padded feature buffer
  __half2* x0h = (__half2*)alloc(NDP * 2);   // tanh(x), row-major
  __half2* x0n = (__half2*)alloc(NDP * 2);   // tanh(x)*no, row-major
  __half2* hA = (__half2*)alloc(NDP * 2);    // row-major h ping
  __half2* hB = (__half2*)alloc(NDP * 2);    // row-major h pong; later zg packed
  __half2* zx = (__half2*)alloc(NDP * 2);    // packed (1+e2)*x0 + agg(x0)
  __half2* z1p = (__half2*)alloc(NDP * 2);   // packed (1+e1)*h5 + agg(h5)
  __half2* g1h = (__half2*)alloc(NDP * 2);   // GIN1 out, row-major
  _Float16* w1p = (_Float16*)alloc(128 * 128 * 2);
  _Float16* w2p = (_Float16*)alloc(256 * 128 * 2);
  int* co = (int*)alloc(NN * 4);
  int* fillc = (int*)alloc(NN * 4);
  float* nrm_o = (float*)alloc(NN * 4);
  float* nrm_i = (float*)alloc(NN * 4);
  int* incl = (int*)alloc(NN * 4);
  int* bsum = (int*)alloc(64 * 4);
  int* boff = (int*)alloc(64 * 4);
  int* rp = (int*)alloc((NN + 1) * 4);
  int* tseq = (int*)alloc(NE * 4);
  int* colsrc = (int*)alloc(NE * 4);

  hipMemsetAsync(co, 0, NN * 4, stream);
  hipMemsetAsync(fillc, 0, NN * 4, stream);

  const int EB = (NE + 255) / 256;
  k_fill2<<<EB, 256, 0, stream>>>(src, dst, co, fillc, tseq);
  k_norm<<<(NN + 255) / 256, 256, 0, stream>>>(co, fillc, nrm_o, nrm_i);

  const int SB = (NN + 1023) / 1024;  // 49
  k_scanA<<<SB, 1024, 0, stream>>>(fillc, incl, bsum);
  k_scanB<<<1, 64, 0, stream>>>(bsum, boff, SB);
  k_scanC<<<(NN + 255) / 256, 256, 0, stream>>>(incl, fillc, boff, rp);
  k_scatter<<<EB, 256, 0, stream>>>(src, dst, tseq, rp, colsrc);

  k_tanh<<<(NN * 32 + 255) / 256, 256, 0, stream>>>(x, nrm_o, x0h, x0n);
  k_wt<<<192, 256, 0, stream>>>(W1, W2, w1p, w2p);

  const int GB = (NN * 64 + 255) / 256;  // one wave per node
  const float4* x0hf = (const float4*)x0h;
  const float4* x0nf = (const float4*)x0n;
  float4* hAf = (float4*)hA;
  float4* hBf = (float4*)hB;

  // Feature-half-blocked gather phases: all stages for half 0, then half 1.
  for (int hf = 0; hf < 2; ++hf) {
    // zx = (1+eps2)*x0 + agg(x0)  [packed]
    k_gz_h<<<GB, 256, 0, stream>>>(x0hf, eps2, rp, colsrc, (_Float16*)zx, hf);
    // APPNP iters 1..5 (sources pre-scaled by no; last one unscaled output)
    k_appnp_h<true><<<GB, 256, 0, stream>>>(x0nf, x0hf, nrm_o, nrm_i, rp, colsrc, hAf, hf);
    k_appnp_h<true><<<GB, 256, 0, stream>>>(hAf, x0hf, nrm_o, nrm_i, rp, colsrc, hBf, hf);
    k_appnp_h<true><<<GB, 256, 0, stream>>>(hBf, x0hf, nrm_o, nrm_i, rp, colsrc, hAf, hf);
    k_appnp_h<true><<<GB, 256, 0, stream>>>(hAf, x0hf, nrm_o, nrm_i, rp, colsrc, hBf, hf);
    k_appnp_h<false><<<GB, 256, 0, stream>>>(hBf, x0hf, nrm_o, nrm_i, rp, colsrc, hAf, hf);
    // z1 = (1+eps1)*h5 + agg(h5)  [packed]
    k_gz_h<<<GB, 256, 0, stream>>>((const float4*)hAf, eps1, rp, colsrc,
                                   (_Float16*)z1p, hf);
  }

  // GIN1: g1 = z1 @ W1 + b1 -> fp16 row-major
  k_mgemm<128, false><<<NT, 64, 0, stream>>>((const _Float16*)z1p, nullptr, w1p, b1,
                                             nullptr, g1h);
  // zg = (1+eps2)*g1 + agg(g1)  [packed, into hB]
  for (int hf = 0; hf < 2; ++hf)
    k_gz_h<<<GB, 256, 0, stream>>>((const float4*)g1h, eps2, rp, colsrc,
                                   (_Float16*)hB, hf);
  // GIN2: out = mish([zg | zx] @ W2 + b2)
  k_mgemm<256, true><<<NT, 64, 0, stream>>>((const _Float16*)hB, (const _Float16*)zx,
                                            w2p, b2, out, nullptr);
}

// Round 7
// 354.685 us; speedup vs baseline: 1.3360x; 1.3360x over previous
//
#include <hip/hip_runtime.h>
#include <hip/hip_fp16.h>
#include <math.h>

#define NN 50000
#define NE 600000
#define NT ((NN + 31) / 32)   // 1563 row-tiles of 32

typedef _Float16 half8_t __attribute__((ext_vector_type(8)));
typedef float f32x16 __attribute__((ext_vector_type(16)));
typedef float f32x2 __attribute__((ext_vector_type(2)));

union F2H { float2 f; __half2 h[2]; };

// fp8 e4m3 encode/decode via gfx950 HW cvt (self-consistent pair)
__device__ __forceinline__ float2 fp8_dec(unsigned short u) {
  f32x2 v = __builtin_amdgcn_cvt_pk_f32_fp8((unsigned int)u, false);
  float2 r; r.x = v.x; r.y = v.y; return r;
}
__device__ __forceinline__ unsigned short fp8_enc(float a, float b) {
  return (unsigned short)__builtin_amdgcn_cvt_pk_fp8_f32(a, b, 0u, false);
}

// Packed fragment layout for MFMA (32x32x16_f16):
//   element (row r in tile t, feature k): ks=k>>4, g=(k&15)>>3, j=k&7
//   halves index = ((t*8 + ks)*64 + g*32 + r)*8 + j   (per 128-k buffer)

// -------- tanh + fp16 write (plain) + fp8 write (*norm_o, APPNP source) ----
__global__ __launch_bounds__(256) void k_tanh(const float* __restrict__ x,
                                              const float* __restrict__ no,
                                              __half2* __restrict__ x0h,
                                              unsigned int* __restrict__ x0n8) {
  int i = blockIdx.x * 256 + threadIdx.x;
  if (i >= NN * 32) return;
  float4 v = reinterpret_cast<const float4*>(x)[i];
  float t[4];
  float vv[4] = {v.x, v.y, v.z, v.w};
  #pragma unroll
  for (int j = 0; j < 4; ++j) {
    float xc = fminf(fmaxf(vv[j], -9.f), 9.f);
    float E = __expf(2.f * xc);
    t[j] = (E - 1.f) / (E + 1.f);
  }
  float s = no[i >> 5];  // 32 float4 per node row
  F2H a;
  a.h[0] = __floats2half2_rn(t[0], t[1]);
  a.h[1] = __floats2half2_rn(t[2], t[3]);
  reinterpret_cast<float2*>(x0h)[i] = a.f;
  unsigned int p = __builtin_amdgcn_cvt_pk_fp8_f32(t[0] * s, t[1] * s, 0u, false);
  p = __builtin_amdgcn_cvt_pk_fp8_f32(t[2] * s, t[3] * s, p, true);
  x0n8[i] = p;
}

// ------------- W transpose -> fragment-packed fp16 (runs once, tiny) --------
__global__ __launch_bounds__(256) void k_wt(const float* __restrict__ W1,
                                            const float* __restrict__ W2,
                                            _Float16* __restrict__ w1p,
                                            _Float16* __restrict__ w2p) {
  int i = blockIdx.x * 256 + threadIdx.x;
  if (i < 128 * 128) {
    int k = i >> 7, n = i & 127;
    int nb = n >> 5, r = n & 31, ks = k >> 4, g = (k & 15) >> 3, j = k & 7;
    w1p[(((ks << 2) + nb) * 64 + (g << 5) + r) * 8 + j] = (_Float16)W1[i];
  } else {
    int q = i - 128 * 128;
    if (q < 256 * 128) {
      int k = q >> 7, n = q & 127;
      int nb = n >> 5, r = n & 31, ks = k >> 4, g = (k & 15) >> 3, j = k & 7;
      w2p[(((ks << 2) + nb) * 64 + (g << 5) + r) * 8 + j] = (_Float16)W2[q];
    }
  }
}

// ---------------- degree count ----------------
__global__ __launch_bounds__(256) void k_deg(const int* __restrict__ src,
                                             const int* __restrict__ dst,
                                             int* __restrict__ co,
                                             int* __restrict__ ci) {
  int e = blockIdx.x * 256 + threadIdx.x;
  if (e < NE) {
    atomicAdd(&co[src[e]], 1);
    atomicAdd(&ci[dst[e]], 1);
  }
}

__global__ __launch_bounds__(256) void k_norm(const int* __restrict__ co,
                                              const int* __restrict__ ci,
                                              float* __restrict__ no,
                                              float* __restrict__ ni) {
  int i = blockIdx.x * 256 + threadIdx.x;
  if (i < NN) {
    no[i] = rsqrtf((float)max(co[i], 1));
    ni[i] = rsqrtf((float)max(ci[i], 1));
  }
}

// ---------------- exclusive scan of in-degrees ----------------
__global__ __launch_bounds__(1024) void k_scanA(const int* __restrict__ deg,
                                                int* __restrict__ incl,
                                                int* __restrict__ bsum) {
  int tid = threadIdx.x;
  int gid = blockIdx.x * 1024 + tid;
  int v = (gid < NN) ? deg[gid] : 0;
  int lane = tid & 63;
  #pragma unroll
  for (int o = 1; o < 64; o <<= 1) {
    int n = __shfl_up(v, o);
    if (lane >= o) v += n;
  }
  __shared__ int ws[16];
  int wid = tid >> 6;
  if (lane == 63) ws[wid] = v;
  __syncthreads();
  if (tid < 16) {
    int s = ws[tid];
    #pragma unroll
    for (int o = 1; o < 16; o <<= 1) {
      int n = __shfl_up(s, o);
      if (tid >= o) s += n;
    }
    ws[tid] = s;
  }
  __syncthreads();
  if (wid > 0) v += ws[wid - 1];
  if (gid < NN) incl[gid] = v;
  if (tid == 1023) bsum[blockIdx.x] = v;
}

__global__ __launch_bounds__(64) void k_scanB(const int* __restrict__ bsum,
                                              int* __restrict__ boff, int nb) {
  int t = threadIdx.x;
  int v = (t < nb) ? bsum[t] : 0;
  int orig = v;
  #pragma unroll
  for (int o = 1; o < 64; o <<= 1) {
    int n = __shfl_up(v, o);
    if (t >= o) v += n;
  }
  if (t < nb) boff[t] = v - orig;  // exclusive
}

__global__ __launch_bounds__(256) void k_scanC(const int* __restrict__ incl,
                                               const int* __restrict__ deg,
                                               const int* __restrict__ boff,
                                               int* __restrict__ rp) {
  int i = blockIdx.x * 256 + threadIdx.x;
  if (i < NN) rp[i] = incl[i] - deg[i] + boff[i >> 10];
  if (i == 0) rp[NN] = NE;
}

// ---------------- CSR bucket fill ----------------
__global__ __launch_bounds__(256) void k_fill(const int* __restrict__ src,
                                              const int* __restrict__ dst,
                                              const int* __restrict__ rp,
                                              int* __restrict__ fill,
                                              int* __restrict__ colsrc) {
  int e = blockIdx.x * 256 + threadIdx.x;
  if (e < NE) {
    int d = dst[e];
    int pos = rp[d] + atomicAdd(&fill[d], 1);
    colsrc[pos] = src[e];
  }
}

#define GATHER_LOOP(LOADEXPR)                                        \
  for (int base = 0; base < cnt; base += 64) {                      \
    int e = beg + base + lane;                                      \
    int cv = (e < end) ? cs[e] : 0;                                 \
    int m = cnt - base; if (m > 64) m = 64;                         \
    int j = 0;                                                      \
    for (; j + 8 <= m; j += 8) {                                    \
      _Pragma("unroll")                                             \
      for (int u = 0; u < 8; ++u) {                                 \
        int s = __builtin_amdgcn_readlane(cv, j + u);               \
        LOADEXPR;                                                   \
      }                                                             \
    }                                                               \
    for (; j < m; ++j) {                                            \
      int s = __builtin_amdgcn_readlane(cv, j);                     \
      LOADEXPR;                                                     \
    }                                                               \
  }

// ---- APPNP iteration (fp8 source): r = 0.8*ni*sum(h8[s]) + 0.2*x0 ----------
// LAST=false: write fp8 scaled by no (next iteration's source).
// LAST=true:  write fp16 unscaled (h5).
template <bool LAST>
__global__ __launch_bounds__(256) void k_appnp8(const unsigned short* __restrict__ h8,
                                                const __half2* __restrict__ x0,
                                                const float* __restrict__ no,
                                                const float* __restrict__ ni,
                                                const int* __restrict__ rp,
                                                const int* __restrict__ cs,
                                                unsigned short* __restrict__ out8,
                                                __half2* __restrict__ out16) {
  int w = (blockIdx.x * 256 + threadIdx.x) >> 6;
  int lane = threadIdx.x & 63;
  if (w >= NN) return;
  const unsigned short* hl = h8 + lane;
  int beg = rp[w], end = rp[w + 1], cnt = end - beg;
  float ax = 0.f, ay = 0.f;
  GATHER_LOOP({
    float2 f = fp8_dec(hl[s * 64]);
    ax += f.x; ay += f.y;
  })
  float wi = 0.8f * ni[w];
  float2 xv = __half22float2(x0[w * 64 + lane]);
  float rx = wi * ax + 0.2f * xv.x;
  float ry = wi * ay + 0.2f * xv.y;
  if (LAST) {
    out16[w * 64 + lane] = __floats2half2_rn(rx, ry);
  } else {
    float sc = no[w];
    out8[w * 64 + lane] = fp8_enc(rx * sc, ry * sc);
  }
}

// packed-store helper: thread (node w, lane) holds features (2*lane, 2*lane+1)
__device__ inline void store_packed(_Float16* __restrict__ zp, int w, int lane,
                                    float v0, float v1) {
  int t = w >> 5, r = w & 31;
  int ks = lane >> 3, g = (lane >> 2) & 1, j = (lane & 3) * 2;
  size_t addr = (((size_t)t * 8 + ks) * 64 + g * 32 + r) * 8 + j;
  *reinterpret_cast<__half2*>(zp + addr) = __floats2half2_rn(v0, v1);
}

// ---- first APPNP pass fused with agg(x0): dual gather (x0*no fp8, x0 fp16) -
// hout8 = fp8( no*(0.8*ni*sum(x0n8[s]) + 0.2*x0[w]) )
// zout(packed fp16) = (1+eps2)*x0[w] + sum(x0[s])
__global__ __launch_bounds__(256) void k_appnp_first(const unsigned short* __restrict__ xs8,
                                                     const __half2* __restrict__ xp,
                                                     const float* __restrict__ epsp,
                                                     const float* __restrict__ no,
                                                     const float* __restrict__ ni,
                                                     const int* __restrict__ rp,
                                                     const int* __restrict__ cs,
                                                     unsigned short* __restrict__ hout8,
                                                     _Float16* __restrict__ zout) {
  int w = (blockIdx.x * 256 + threadIdx.x) >> 6;
  int lane = threadIdx.x & 63;
  if (w >= NN) return;
  const unsigned short* xsl = xs8 + lane;
  const __half2* xpl = xp + lane;
  int beg = rp[w], end = rp[w + 1], cnt = end - beg;
  float ax = 0.f, ay = 0.f, bx = 0.f, by = 0.f;
  GATHER_LOOP({
    float2 f = fp8_dec(xsl[s * 64]);
    float2 g2 = __half22float2(xpl[s * 64]);
    ax += f.x; ay += f.y; bx += g2.x; by += g2.y;
  })
  float2 xv = __half22float2(xp[w * 64 + lane]);
  float wi = 0.8f * ni[w];
  float sc = no[w];
  hout8[w * 64 + lane] = fp8_enc(sc * (wi * ax + 0.2f * xv.x),
                                 sc * (wi * ay + 0.2f * xv.y));
  float e2 = 1.0f + epsp[0];
  store_packed(zout, w, lane, e2 * xv.x + bx, e2 * xv.y + by);
}

// ---- gather + GIN affine, packed out: z = (1+eps)*h[w] + sum(h[s]) ---------
__global__ __launch_bounds__(256) void k_gather_z(const __half2* __restrict__ h,
                                                  const float* __restrict__ epsp,
                                                  const int* __restrict__ rp,
                                                  const int* __restrict__ cs,
                                                  _Float16* __restrict__ zout) {
  int w = (blockIdx.x * 256 + threadIdx.x) >> 6;
  int lane = threadIdx.x & 63;
  if (w >= NN) return;
  const __half2* hl = h + lane;
  int beg = rp[w], end = rp[w + 1], cnt = end - beg;
  float ax = 0.f, ay = 0.f;
  GATHER_LOOP({
    float2 f = __half22float2(hl[s * 64]);
    ax += f.x; ay += f.y;
  })
  float e1 = 1.0f + epsp[0];
  float2 hv = __half22float2(h[w * 64 + lane]);
  store_packed(zout, w, lane, e1 * hv.x + ax, e1 * hv.y + ay);
}

// ---- MFMA GEMM on packed operands: C = Z @ W + b -------------------------
template <int KTOT, bool MISH>
__global__ __launch_bounds__(64) void k_mgemm(const _Float16* __restrict__ z0,
                                              const _Float16* __restrict__ z1,
                                              const _Float16* __restrict__ wp,
                                              const float* __restrict__ bias,
                                              float* __restrict__ outf,
                                              __half2* __restrict__ outh) {
  int lane = threadIdx.x;
  int t = blockIdx.x;
  int row0 = t * 32;
  if (row0 >= NN) return;
  int r31 = lane & 31, g = lane >> 5;
  f32x16 acc[4];
  #pragma unroll
  for (int i = 0; i < 4; ++i) acc[i] = (f32x16)(0.0f);
  #pragma unroll 4
  for (int ks = 0; ks < KTOT / 16; ++ks) {
    const _Float16* zp = (KTOT == 256 && ks >= 8) ? z1 : z0;
    int kls = (KTOT == 256) ? (ks & 7) : ks;
    half8_t a = *reinterpret_cast<const half8_t*>(
        zp + (((size_t)t * 8 + kls) * 64 + lane) * 8);
    #pragma unroll
    for (int nb = 0; nb < 4; ++nb) {
      half8_t b = *reinterpret_cast<const half8_t*>(
          wp + (((size_t)ks * 4 + nb) * 64 + lane) * 8);
      acc[nb] = __builtin_amdgcn_mfma_f32_32x32x16_f16(a, b, acc[nb], 0, 0, 0);
    }
  }
  #pragma unroll
  for (int nb = 0; nb < 4; ++nb) {
    float bv = bias[nb * 32 + r31];
    #pragma unroll
    for (int r = 0; r < 16; ++r) {
      int rl = (r & 3) + 8 * (r >> 2) + 4 * g;
      int grow = row0 + rl;
      if (grow < NN) {
        float v = acc[nb][r] + bv;
        if (MISH) {
          // mish(v) = v*q/(q+2), q = E(E+2), E = e^v
          float E = __expf(v);
          float q = E * (E + 2.f);
          float mv = v * q / (q + 2.f);
          v = (v > 15.f) ? v : mv;
          outf[(size_t)grow * 128 + nb * 32 + r31] = v;
        } else {
          float u = __shfl_xor(v, 1);
          if (!(lane & 1)) {
            outh[((size_t)grow * 128 + nb * 32 + r31) >> 1] = __floats2half2_rn(v, u);
          }
        }
      }
    }
  }
}

extern "C" void kernel_launch(void* const* d_in, const int* in_sizes, int n_in,
                              void* d_out, int out_size, void* d_ws, size_t ws_size,
                              hipStream_t stream) {
  const float* x = (const float*)d_in[0];
  const int* src = (const int*)d_in[1];
  const int* dst = (const int*)d_in[2];
  const float* W1 = (const float*)d_in[3];
  const float* b1 = (const float*)d_in[4];
  const float* W2 = (const float*)d_in[5];
  const float* b2 = (const float*)d_in[6];
  const float* eps1 = (const float*)d_in[7];
  const float* eps2 = (const float*)d_in[8];
  float* out = (float*)d_out;

  char* ws = (char*)d_ws;
  size_t off = 0;
  auto alloc = [&](size_t bytes) -> void* {
    void* p = ws + off;
    off += (bytes + 255) & ~(size_t)255;
    return p;
  };
  const size_t NDP = (size_t)NT * 4096;  // halves per padded fp16 buffer
  __half2* x0h = (__half2*)alloc(NDP * 2);         // tanh(x), fp16 row-major
  unsigned short* x0n8 = (unsigned short*)alloc(NDP);  // fp8 tanh(x)*no
  unsigned short* hA8 = (unsigned short*)alloc(NDP);   // fp8 APPNP ping
  unsigned short* hB8 = (unsigned short*)alloc(NDP);   // fp8 APPNP pong
  __half2* h5 = (__half2*)alloc(NDP * 2);          // fp16 APPNP output
  __half2* zx = (__half2*)alloc(NDP * 2);          // packed (1+e2)*x0+agg(x0)
  __half2* z1p = (__half2*)alloc(NDP * 2);         // packed (1+e1)*h5+agg(h5)
  __half2* g1h = (__half2*)alloc(NDP * 2);         // GIN1 out, fp16 row-major
  __half2* zg = (__half2*)alloc(NDP * 2);          // packed (1+e2)*g1+agg(g1)
  _Float16* w1p = (_Float16*)alloc(128 * 128 * 2);
  _Float16* w2p = (_Float16*)alloc(256 * 128 * 2);
  int* cnt_o = (int*)alloc(NN * 4);
  int* cnt_i = (int*)alloc(NN * 4);
  float* nrm_o = (float*)alloc(NN * 4);
  float* nrm_i = (float*)alloc(NN * 4);
  int* incl = (int*)alloc(NN * 4);
  int* bsum = (int*)alloc(64 * 4);
  int* boff = (int*)alloc(64 * 4);
  int* rp = (int*)alloc((NN + 1) * 4);
  int* fillc = (int*)alloc(NN * 4);
  int* colsrc = (int*)alloc(NE * 4);

  hipMemsetAsync(cnt_o, 0, NN * 4, stream);
  hipMemsetAsync(cnt_i, 0, NN * 4, stream);
  hipMemsetAsync(fillc, 0, NN * 4, stream);

  const int EB = (NE + 255) / 256;
  k_deg<<<EB, 256, 0, stream>>>(src, dst, cnt_o, cnt_i);
  k_norm<<<(NN + 255) / 256, 256, 0, stream>>>(cnt_o, cnt_i, nrm_o, nrm_i);

  const int SB = (NN + 1023) / 1024;  // 49
  k_scanA<<<SB, 1024, 0, stream>>>(cnt_i, incl, bsum);
  k_scanB<<<1, 64, 0, stream>>>(bsum, boff, SB);
  k_scanC<<<(NN + 255) / 256, 256, 0, stream>>>(incl, cnt_i, boff, rp);
  k_fill<<<EB, 256, 0, stream>>>(src, dst, rp, fillc, colsrc);

  k_tanh<<<(NN * 32 + 255) / 256, 256, 0, stream>>>(x, nrm_o, x0h,
                                                    (unsigned int*)x0n8);
  k_wt<<<192, 256, 0, stream>>>(W1, W2, w1p, w2p);

  const int GB = (NN * 64 + 255) / 256;  // one wave per node
  // APPNP iter1 fused with agg(x0): -> hA8 (fp8, scaled), zx (packed fp16)
  k_appnp_first<<<GB, 256, 0, stream>>>(x0n8, x0h, eps2, nrm_o, nrm_i, rp, colsrc,
                                        hA8, (_Float16*)zx);
  // APPNP iters 2..4 (fp8->fp8 scaled), iter 5 (fp8->fp16 unscaled)
  k_appnp8<false><<<GB, 256, 0, stream>>>(hA8, x0h, nrm_o, nrm_i, rp, colsrc,
                                          hB8, nullptr);
  k_appnp8<false><<<GB, 256, 0, stream>>>(hB8, x0h, nrm_o, nrm_i, rp, colsrc,
                                          hA8, nullptr);
  k_appnp8<false><<<GB, 256, 0, stream>>>(hA8, x0h, nrm_o, nrm_i, rp, colsrc,
                                          hB8, nullptr);
  k_appnp8<true><<<GB, 256, 0, stream>>>(hB8, x0h, nrm_o, nrm_i, rp, colsrc,
                                         nullptr, h5);

  // z1(packed) = (1+eps1)*h5 + agg(h5)
  k_gather_z<<<GB, 256, 0, stream>>>(h5, eps1, rp, colsrc, (_Float16*)z1p);

  // GIN1: g1 = z1 @ W1 + b1 -> fp16 row-major
  k_mgemm<128, false><<<NT, 64, 0, stream>>>((const _Float16*)z1p, nullptr, w1p, b1,
                                             nullptr, g1h);
  // zg(packed) = (1+eps2)*g1 + agg(g1)
  k_gather_z<<<GB, 256, 0, stream>>>(g1h, eps2, rp, colsrc, (_Float16*)zg);
  // GIN2: out = mish([zg | zx] @ W2 + b2)
  k_mgemm<256, true><<<NT, 64, 0, stream>>>((const _Float16*)zg, (const _Float16*)zx,
                                            w2p, b2, out, nullptr);
}

// Round 9
// 332.736 us; speedup vs baseline: 1.4241x; 1.0660x over previous
//
#include <hip/hip_runtime.h>
#include <hip/hip_fp16.h>
#include <math.h>

#define NN 50000
#define NE 600000
#define NT ((NN + 31) / 32)   // 1563 row-tiles of 32

// histogram degree-count params
#define HB 64        // histogram blocks
#define HBINS 12500  // bins per phase (50KB LDS); 4 ranges x {src,dst} = 8 phases

typedef _Float16 half8_t __attribute__((ext_vector_type(8)));
typedef float f32x16 __attribute__((ext_vector_type(16)));
typedef float f32x2 __attribute__((ext_vector_type(2)));

union F2H { float2 f; __half2 h[2]; };

// fp8 e4m3 encode/decode via gfx950 HW cvt (self-consistent pair)
__device__ __forceinline__ float2 fp8_dec(unsigned short u) {
  f32x2 v = __builtin_amdgcn_cvt_pk_f32_fp8((unsigned int)u, false);
  float2 r; r.x = v.x; r.y = v.y; return r;
}
__device__ __forceinline__ unsigned short fp8_enc(float a, float b) {
  return (unsigned short)__builtin_amdgcn_cvt_pk_fp8_f32(a, b, 0u, false);
}

// Packed fragment layout for MFMA (32x32x16_f16):
//   element (row r in tile t, feature k): ks=k>>4, g=(k&15)>>3, j=k&7
//   halves index = ((t*8 + ks)*64 + g*32 + r)*8 + j   (per 128-k buffer)

// -- tanh -> fp16 (self/residual) + fp8*no (APPNP source) --------------------
__global__ __launch_bounds__(256) void k_tanh(const float* __restrict__ x,
                                              const float* __restrict__ no,
                                              __half2* __restrict__ x0h,
                                              unsigned int* __restrict__ x0n8) {
  int i = blockIdx.x * 256 + threadIdx.x;
  if (i >= NN * 32) return;
  float4 v = reinterpret_cast<const float4*>(x)[i];
  float t[4];
  float vv[4] = {v.x, v.y, v.z, v.w};
  #pragma unroll
  for (int j = 0; j < 4; ++j) {
    float xc = fminf(fmaxf(vv[j], -9.f), 9.f);
    float E = __expf(2.f * xc);
    t[j] = (E - 1.f) / (E + 1.f);
  }
  float s = no[i >> 5];  // 32 float4 per node row
  F2H a;
  a.h[0] = __floats2half2_rn(t[0], t[1]);
  a.h[1] = __floats2half2_rn(t[2], t[3]);
  reinterpret_cast<float2*>(x0h)[i] = a.f;
  unsigned int p = __builtin_amdgcn_cvt_pk_fp8_f32(t[0] * s, t[1] * s, 0u, false);
  p = __builtin_amdgcn_cvt_pk_fp8_f32(t[2] * s, t[3] * s, p, true);
  x0n8[i] = p;
}

// ------------- W transpose -> fragment-packed fp16 (runs once, tiny) --------
__global__ __launch_bounds__(256) void k_wt(const float* __restrict__ W1,
                                            const float* __restrict__ W2,
                                            _Float16* __restrict__ w1p,
                                            _Float16* __restrict__ w2p) {
  int i = blockIdx.x * 256 + threadIdx.x;
  if (i < 128 * 128) {
    int k = i >> 7, n = i & 127;
    int nb = n >> 5, r = n & 31, ks = k >> 4, g = (k & 15) >> 3, j = k & 7;
    w1p[(((ks << 2) + nb) * 64 + (g << 5) + r) * 8 + j] = (_Float16)W1[i];
  } else {
    int q = i - 128 * 128;
    if (q < 256 * 128) {
      int k = q >> 7, n = q & 127;
      int nb = n >> 5, r = n & 31, ks = k >> 4, g = (k & 15) >> 3, j = k & 7;
      w2p[(((ks << 2) + nb) * 64 + (g << 5) + r) * 8 + j] = (_Float16)W2[q];
    }
  }
}

// ---- degree count via LDS-privatized histogram (no global atomics) --------
// 8 phases: type (src/out-deg, dst/in-deg) x 4 bin ranges of HBINS.
// Partials written coalesced to hpart[ph][block][bin].
__global__ __launch_bounds__(1024) void k_hist(const int* __restrict__ src,
                                               const int* __restrict__ dst,
                                               int* __restrict__ hpart) {
  __shared__ int lh[HBINS];
  #pragma unroll 1
  for (int ph = 0; ph < 8; ++ph) {
    const int* idx = (ph & 4) ? dst : src;
    int base = (ph & 3) * HBINS;
    for (int i = threadIdx.x; i < HBINS; i += 1024) lh[i] = 0;
    __syncthreads();
    for (int e = blockIdx.x * 1024 + threadIdx.x; e < NE; e += HB * 1024) {
      int v = idx[e] - base;
      if ((unsigned)v < (unsigned)HBINS) atomicAdd(&lh[v], 1);
    }
    __syncthreads();
    int* outp = hpart + ((size_t)ph * HB + blockIdx.x) * HBINS;
    for (int i = threadIdx.x; i < HBINS; i += 1024) outp[i] = lh[i];
    __syncthreads();
  }
}

// ---- merge partials -> in-degree (for scan) + both norms -------------------
__global__ __launch_bounds__(256) void k_merge(const int* __restrict__ hpart,
                                               int* __restrict__ ci,
                                               float* __restrict__ no,
                                               float* __restrict__ ni) {
  int i = blockIdx.x * 256 + threadIdx.x;
  if (i >= NN) return;
  int r = i / HBINS, bin = i - r * HBINS;
  const int* ps = hpart + ((size_t)(0 + r) * HB) * HBINS + bin;      // src phases 0..3
  const int* pd = hpart + ((size_t)(4 + r) * HB) * HBINS + bin;      // dst phases 4..7
  int so = 0, si = 0;
  #pragma unroll 8
  for (int b = 0; b < HB; ++b) {
    so += ps[(size_t)b * HBINS];
    si += pd[(size_t)b * HBINS];
  }
  ci[i] = si;
  no[i] = rsqrtf((float)max(so, 1));
  ni[i] = rsqrtf((float)max(si, 1));
}

// ---------------- exclusive scan of in-degrees ----------------
__global__ __launch_bounds__(1024) void k_scanA(const int* __restrict__ deg,
                                                int* __restrict__ incl,
                                                int* __restrict__ bsum) {
  int tid = threadIdx.x;
  int gid = blockIdx.x * 1024 + tid;
  int v = (gid < NN) ? deg[gid] : 0;
  int lane = tid & 63;
  #pragma unroll
  for (int o = 1; o < 64; o <<= 1) {
    int n = __shfl_up(v, o);
    if (lane >= o) v += n;
  }
  __shared__ int ws[16];
  int wid = tid >> 6;
  if (lane == 63) ws[wid] = v;
  __syncthreads();
  if (tid < 16) {
    int s = ws[tid];
    #pragma unroll
    for (int o = 1; o < 16; o <<= 1) {
      int n = __shfl_up(s, o);
      if (tid >= o) s += n;
    }
    ws[tid] = s;
  }
  __syncthreads();
  if (wid > 0) v += ws[wid - 1];
  if (gid < NN) incl[gid] = v;
  if (tid == 1023) bsum[blockIdx.x] = v;
}

__global__ __launch_bounds__(64) void k_scanB(const int* __restrict__ bsum,
                                              int* __restrict__ boff, int nb) {
  int t = threadIdx.x;
  int v = (t < nb) ? bsum[t] : 0;
  int orig = v;
  #pragma unroll
  for (int o = 1; o < 64; o <<= 1) {
    int n = __shfl_up(v, o);
    if (t >= o) v += n;
  }
  if (t < nb) boff[t] = v - orig;  // exclusive
}

__global__ __launch_bounds__(256) void k_scanC(const int* __restrict__ incl,
                                               const int* __restrict__ deg,
                                               const int* __restrict__ boff,
                                               int* __restrict__ rp) {
  int i = blockIdx.x * 256 + threadIdx.x;
  if (i < NN) rp[i] = incl[i] - deg[i] + boff[i >> 10];
  if (i == 0) rp[NN] = NE;
}

// ---------------- CSR bucket fill ----------------
__global__ __launch_bounds__(256) void k_fill(const int* __restrict__ src,
                                              const int* __restrict__ dst,
                                              const int* __restrict__ rp,
                                              int* __restrict__ fill,
                                              int* __restrict__ colsrc) {
  int e = blockIdx.x * 256 + threadIdx.x;
  if (e < NE) {
    int d = dst[e];
    int pos = rp[d] + atomicAdd(&fill[d], 1);
    colsrc[pos] = src[e];
  }
}

#define GATHER_LOOP(LOADEXPR)                                        \
  for (int base = 0; base < cnt; base += 64) {                      \
    int e = beg + base + lane;                                      \
    int cv = (e < end) ? cs[e] : 0;                                 \
    int m = cnt - base; if (m > 64) m = 64;                         \
    int j = 0;                                                      \
    for (; j + 8 <= m; j += 8) {                                    \
      _Pragma("unroll")                                             \
      for (int u = 0; u < 8; ++u) {                                 \
        int s = __builtin_amdgcn_readlane(cv, j + u);               \
        LOADEXPR;                                                   \
      }                                                             \
    }                                                               \
    for (; j < m; ++j) {                                            \
      int s = __builtin_amdgcn_readlane(cv, j);                     \
      LOADEXPR;                                                     \
    }                                                               \
  }

// ---- APPNP iteration (fp8 source): r = 0.8*ni*sum(h8[s]) + 0.2*x0 ----------
// LAST=false: write fp8 scaled by no (next iteration's source).
// LAST=true:  write fp16 unscaled (h5).
template <bool LAST>
__global__ __launch_bounds__(256) void k_appnp8(const unsigned short* __restrict__ h8,
                                                const __half2* __restrict__ x0,
                                                const float* __restrict__ no,
                                                const float* __restrict__ ni,
                                                const int* __restrict__ rp,
                                                const int* __restrict__ cs,
                                                unsigned short* __restrict__ out8,
                                                __half2* __restrict__ out16) {
  int w = (blockIdx.x * 256 + threadIdx.x) >> 6;
  int lane = threadIdx.x & 63;
  if (w >= NN) return;
  const unsigned short* hl = h8 + lane;
  int beg = rp[w], end = rp[w + 1], cnt = end - beg;
  float ax = 0.f, ay = 0.f;
  GATHER_LOOP({
    float2 f = fp8_dec(hl[s * 64]);
    ax += f.x; ay += f.y;
  })
  float wi = 0.8f * ni[w];
  float2 xv = __half22float2(x0[w * 64 + lane]);
  float rx = wi * ax + 0.2f * xv.x;
  float ry = wi * ay + 0.2f * xv.y;
  if (LAST) {
    out16[w * 64 + lane] = __floats2half2_rn(rx, ry);
  } else {
    float sc = no[w];
    out8[w * 64 + lane] = fp8_enc(rx * sc, ry * sc);
  }
}

// packed-store helper: thread (node w, lane) holds features (2*lane, 2*lane+1)
__device__ inline void store_packed(_Float16* __restrict__ zp, int w, int lane,
                                    float v0, float v1) {
  int t = w >> 5, r = w & 31;
  int ks = lane >> 3, g = (lane >> 2) & 1, j = (lane & 3) * 2;
  size_t addr = (((size_t)t * 8 + ks) * 64 + g * 32 + r) * 8 + j;
  *reinterpret_cast<__half2*>(zp + addr) = __floats2half2_rn(v0, v1);
}

// ---- first APPNP pass fused with agg(x0): dual gather (x0*no fp8, x0 fp16) -
// hout8 = fp8( no*(0.8*ni*sum(x0n8[s]) + 0.2*x0[w]) )
// zout(packed fp16) = (1+eps2)*x0[w] + sum(x0[s])
__global__ __launch_bounds__(256) void k_appnp_first(const unsigned short* __restrict__ xs8,
                                                     const __half2* __restrict__ xp,
                                                     const float* __restrict__ epsp,
                                                     const float* __restrict__ no,
                                                     const float* __restrict__ ni,
                                                     const int* __restrict__ rp,
                                                     const int* __restrict__ cs,
                                                     unsigned short* __restrict__ hout8,
                                                     _Float16* __restrict__ zout) {
  int w = (blockIdx.x * 256 + threadIdx.x) >> 6;
  int lane = threadIdx.x & 63;
  if (w >= NN) return;
  const unsigned short* xsl = xs8 + lane;
  const __half2* xpl = xp + lane;
  int beg = rp[w], end = rp[w + 1], cnt = end - beg;
  float ax = 0.f, ay = 0.f, bx = 0.f, by = 0.f;
  GATHER_LOOP({
    float2 f = fp8_dec(xsl[s * 64]);
    float2 g2 = __half22float2(xpl[s * 64]);
    ax += f.x; ay += f.y; bx += g2.x; by += g2.y;
  })
  float2 xv = __half22float2(xp[w * 64 + lane]);
  float wi = 0.8f * ni[w];
  float sc = no[w];
  hout8[w * 64 + lane] = fp8_enc(sc * (wi * ax + 0.2f * xv.x),
                                 sc * (wi * ay + 0.2f * xv.y));
  float e2 = 1.0f + epsp[0];
  store_packed(zout, w, lane, e2 * xv.x + bx, e2 * xv.y + by);
}

// ---- gather + GIN affine, packed out: z = (1+eps)*h[w] + sum(h[s]) ---------
__global__ __launch_bounds__(256) void k_gather_z(const __half2* __restrict__ h,
                                                  const float* __restrict__ epsp,
                                                  const int* __restrict__ rp,
                                                  const int* __restrict__ cs,
                                                  _Float16* __restrict__ zout) {
  int w = (blockIdx.x * 256 + threadIdx.x) >> 6;
  int lane = threadIdx.x & 63;
  if (w >= NN) return;
  const __half2* hl = h + lane;
  int beg = rp[w], end = rp[w + 1], cnt = end - beg;
  float ax = 0.f, ay = 0.f;
  GATHER_LOOP({
    float2 f = __half22float2(hl[s * 64]);
    ax += f.x; ay += f.y;
  })
  float e1 = 1.0f + epsp[0];
  float2 hv = __half22float2(h[w * 64 + lane]);
  store_packed(zout, w, lane, e1 * hv.x + ax, e1 * hv.y + ay);
}

// ---- MFMA GEMM on packed operands: C = Z @ W + b -------------------------
template <int KTOT, bool MISH>
__global__ __launch_bounds__(64) void k_mgemm(const _Float16* __restrict__ z0,
                                              const _Float16* __restrict__ z1,
                                              const _Float16* __restrict__ wp,
                                              const float* __restrict__ bias,
                                              float* __restrict__ outf,
                                              __half2* __restrict__ outh) {
  int lane = threadIdx.x;
  int t = blockIdx.x;
  int row0 = t * 32;
  if (row0 >= NN) return;
  int r31 = lane & 31, g = lane >> 5;
  f32x16 acc[4];
  #pragma unroll
  for (int i = 0; i < 4; ++i) acc[i] = (f32x16)(0.0f);
  #pragma unroll 4
  for (int ks = 0; ks < KTOT / 16; ++ks) {
    const _Float16* zp = (KTOT == 256 && ks >= 8) ? z1 : z0;
    int kls = (KTOT == 256) ? (ks & 7) : ks;
    half8_t a = *reinterpret_cast<const half8_t*>(
        zp + (((size_t)t * 8 + kls) * 64 + lane) * 8);
    #pragma unroll
    for (int nb = 0; nb < 4; ++nb) {
      half8_t b = *reinterpret_cast<const half8_t*>(
          wp + (((size_t)ks * 4 + nb) * 64 + lane) * 8);
      acc[nb] = __builtin_amdgcn_mfma_f32_32x32x16_f16(a, b, acc[nb], 0, 0, 0);
    }
  }
  #pragma unroll
  for (int nb = 0; nb < 4; ++nb) {
    float bv = bias[nb * 32 + r31];
    #pragma unroll
    for (int r = 0; r < 16; ++r) {
      int rl = (r & 3) + 8 * (r >> 2) + 4 * g;
      int grow = row0 + rl;
      if (grow < NN) {
        float v = acc[nb][r] + bv;
        if (MISH) {
          // mish(v) = v*q/(q+2), q = E(E+2), E = e^v
          float E = __expf(v);
          float q = E * (E + 2.f);
          float mv = v * q / (q + 2.f);
          v = (v > 15.f) ? v : mv;
          outf[(size_t)grow * 128 + nb * 32 + r31] = v;
        } else {
          float u = __shfl_xor(v, 1);
          if (!(lane & 1)) {
            outh[((size_t)grow * 128 + nb * 32 + r31) >> 1] = __floats2half2_rn(v, u);
          }
        }
      }
    }
  }
}

extern "C" void kernel_launch(void* const* d_in, const int* in_sizes, int n_in,
                              void* d_out, int out_size, void* d_ws, size_t ws_size,
                              hipStream_t stream) {
  const float* x = (const float*)d_in[0];
  const int* src = (const int*)d_in[1];
  const int* dst = (const int*)d_in[2];
  const float* W1 = (const float*)d_in[3];
  const float* b1 = (const float*)d_in[4];
  const float* W2 = (const float*)d_in[5];
  const float* b2 = (const float*)d_in[6];
  const float* eps1 = (const float*)d_in[7];
  const float* eps2 = (const float*)d_in[8];
  float* out = (float*)d_out;

  char* ws = (char*)d_ws;
  size_t off = 0;
  auto alloc = [&](size_t bytes) -> void* {
    void* p = ws + off;
    off += (bytes + 255) & ~(size_t)255;
    return p;
  };
  const size_t NDP = (size_t)NT * 4096;  // halves per padded fp16 buffer
  __half2* x0h = (__half2*)alloc(NDP * 2);             // tanh(x), fp16
  unsigned short* x0n8 = (unsigned short*)alloc(NDP);  // fp8 tanh(x)*no
  unsigned short* hA8 = (unsigned short*)alloc(NDP);   // fp8 APPNP ping
  unsigned short* hB8 = (unsigned short*)alloc(NDP);   // fp8 APPNP pong
  __half2* h5 = (__half2*)alloc(NDP * 2);              // fp16 APPNP output
  __half2* zx = (__half2*)alloc(NDP * 2);              // packed (1+e2)*x0+agg(x0)
  __half2* z1p = (__half2*)alloc(NDP * 2);             // packed (1+e1)*h5+agg(h5)
  __half2* g1h = (__half2*)alloc(NDP * 2);             // GIN1 out, fp16
  __half2* zg = (__half2*)alloc(NDP * 2);              // packed (1+e2)*g1+agg(g1)
  _Float16* w1p = (_Float16*)alloc(128 * 128 * 2);
  _Float16* w2p = (_Float16*)alloc(256 * 128 * 2);
  int* ci = (int*)alloc(NN * 4);
  int* fillc = (int*)alloc(NN * 4);
  float* nrm_o = (float*)alloc(NN * 4);
  float* nrm_i = (float*)alloc(NN * 4);
  int* incl = (int*)alloc(NN * 4);
  int* bsum = (int*)alloc(64 * 4);
  int* boff = (int*)alloc(64 * 4);
  int* rp = (int*)alloc((NN + 1) * 4);
  int* colsrc = (int*)alloc(NE * 4);

  // histogram partials: 8 phases x HB blocks x HBINS x 4B = 25.6 MB.
  // Aliased over zx+z1p (25.6 MB): those are first written by k_appnp_first /
  // k_gather_z, which run strictly after k_merge has consumed the partials.
  int* hpart = (int*)zx;

  hipMemsetAsync(fillc, 0, NN * 4, stream);

  // degrees via LDS histogram (no global atomics), then norms + scan + CSR
  k_hist<<<HB, 1024, 0, stream>>>(src, dst, hpart);
  k_merge<<<(NN + 255) / 256, 256, 0, stream>>>(hpart, ci, nrm_o, nrm_i);

  const int SB = (NN + 1023) / 1024;  // 49
  k_scanA<<<SB, 1024, 0, stream>>>(ci, incl, bsum);
  k_scanB<<<1, 64, 0, stream>>>(bsum, boff, SB);
  k_scanC<<<(NN + 255) / 256, 256, 0, stream>>>(incl, ci, boff, rp);
  const int EB = (NE + 255) / 256;
  k_fill<<<EB, 256, 0, stream>>>(src, dst, rp, fillc, colsrc);

  k_tanh<<<(NN * 32 + 255) / 256, 256, 0, stream>>>(x, nrm_o, x0h,
                                                    (unsigned int*)x0n8);
  k_wt<<<192, 256, 0, stream>>>(W1, W2, w1p, w2p);

  const int GB = (NN * 64 + 255) / 256;  // one wave per node
  // APPNP iter1 fused with agg(x0): -> hA8 (fp8, scaled), zx (packed fp16)
  k_appnp_first<<<GB, 256, 0, stream>>>(x0n8, x0h, eps2, nrm_o, nrm_i, rp, colsrc,
                                        hA8, (_Float16*)zx);
  // APPNP iters 2..4 (fp8->fp8 scaled), iter 5 (fp8->fp16 unscaled)
  k_appnp8<false><<<GB, 256, 0, stream>>>(hA8, x0h, nrm_o, nrm_i, rp, colsrc,
                                          hB8, nullptr);
  k_appnp8<false><<<GB, 256, 0, stream>>>(hB8, x0h, nrm_o, nrm_i, rp, colsrc,
                                          hA8, nullptr);
  k_appnp8<false><<<GB, 256, 0, stream>>>(hA8, x0h, nrm_o, nrm_i, rp, colsrc,
                                          hB8, nullptr);
  k_appnp8<true><<<GB, 256, 0, stream>>>(hB8, x0h, nrm_o, nrm_i, rp, colsrc,
                                         nullptr, h5);

  // z1(packed) = (1+eps1)*h5 + agg(h5)   [fp16 source]
  k_gather_z<<<GB, 256, 0, stream>>>(h5, eps1, rp, colsrc, (_Float16*)z1p);

  // GIN1: g1 = z1 @ W1 + b1 -> fp16 row-major
  k_mgemm<128, false><<<NT, 64, 0, stream>>>((const _Float16*)z1p, nullptr, w1p, b1,
                                             nullptr, g1h);
  // zg(packed) = (1+eps2)*g1 + agg(g1)   [fp16 source]
  k_gather_z<<<GB, 256, 0, stream>>>(g1h, eps2, rp, colsrc, (_Float16*)zg);
  // GIN2: out = mish([zg | zx] @ W2 + b2)
  k_mgemm<256, true><<<NT, 64, 0, stream>>>((const _Float16*)zg, (const _Float16*)zx,
                                            w2p, b2, out, nullptr);
}